// Round 4
// baseline (290.851 us; speedup 1.0000x reference)
//
#include <hip/hip_runtime.h>
#include <math.h>

#define NPROB (64 * 2048)

__host__ __device__ constexpr int OI6(int i, int j) { return i * 6 - i * (i - 1) / 2 + (j - i); }
__host__ __device__ constexpr int QI(int i, int j)  { return i * 7 - i * (i - 1) / 2 + (j - i); }

// 4 waves per block, all mirroring the same 64 problems (one per lane).
// Wave r builds role-r partials of {y6[13], Omega-upper[21]}; two-phase LDS
// reduction; then every wave redundantly runs the serial solve/expm/update
// (bit-identical: fixed summation order).
__global__ __launch_bounds__(256) void gn5_kernel(const float* __restrict__ Mg,
                                                  const float* __restrict__ Tg,
                                                  float* __restrict__ outg) {
    const int tid  = threadIdx.x;
    const int lane = tid & 63;
    const int wv   = tid >> 6;
    const int prob = blockIdx.x * 64 + lane;

    // LDS: staging view (64*169 fp32 = 43264 B) unioned with the reduction
    // view (17 slots * 4 roles * 64 lanes fp64 = 34816 B). 43264 < 64 KB cap,
    // and 3 blocks/CU fit (129.8 KB of 160 KB) -> 12 waves/CU.
    __shared__ __align__(16) unsigned char smem[64 * 169 * 4];
    float*  sbuf = (float*)smem;
    double* red  = (double*)smem;

    // ---- stage M for this block's 64 problems (coalesced float4) ----
    {
        const float4* src = (const float4*)(Mg + (long long)blockIdx.x * (64 * 169));
        float4* dst = (float4*)smem;
        #pragma unroll 1
        for (int i = tid; i < (64 * 169) / 4; i += 256) dst[i] = src[i];
    }
    __syncthreads();

    // ---- role-specific M extraction (each lane keeps <=28 fp32) ----
    float mf[28];
    {
        const float* mb = sbuf + lane * 169;
        if (wv == 0) {
            // diag block 0 (upper 6), diag block 1 (upper 6), offdiag (0,1) (9)
            mf[0] = mb[0*13+0]; mf[1] = mb[0*13+1]; mf[2] = mb[0*13+2];
            mf[3] = mb[1*13+1]; mf[4] = mb[1*13+2]; mf[5] = mb[2*13+2];
            mf[6] = mb[3*13+3]; mf[7] = mb[3*13+4]; mf[8] = mb[3*13+5];
            mf[9] = mb[4*13+4]; mf[10] = mb[4*13+5]; mf[11] = mb[5*13+5];
            #pragma unroll
            for (int r = 0; r < 3; ++r)
                #pragma unroll
                for (int c = 0; c < 3; ++c) mf[12 + r*3 + c] = mb[r*13 + 3 + c];
        } else if (wv == 1) {
            // diag block 2 (6), offdiag (0,2) (9), ones-row (13)
            mf[0] = mb[6*13+6]; mf[1] = mb[6*13+7]; mf[2] = mb[6*13+8];
            mf[3] = mb[7*13+7]; mf[4] = mb[7*13+8]; mf[5] = mb[8*13+8];
            #pragma unroll
            for (int r = 0; r < 3; ++r)
                #pragma unroll
                for (int c = 0; c < 3; ++c) mf[6 + r*3 + c] = mb[r*13 + 6 + c];
            #pragma unroll
            for (int r = 0; r < 9; ++r) mf[15 + r] = mb[r*13 + 9];
            mf[24] = mb[9*13 + 9];
            #pragma unroll
            for (int s = 0; s < 3; ++s) mf[25 + s] = mb[9*13 + 10 + s];
        } else if (wv == 2) {
            // offdiag (1,2) (9), rot-trans block i=0 (9), Mtt upper (6)
            #pragma unroll
            for (int r = 0; r < 3; ++r)
                #pragma unroll
                for (int c = 0; c < 3; ++c) mf[r*3 + c] = mb[(3 + r)*13 + 6 + c];
            #pragma unroll
            for (int r = 0; r < 3; ++r)
                #pragma unroll
                for (int c = 0; c < 3; ++c) mf[9 + r*3 + c] = mb[r*13 + 10 + c];
            mf[18] = mb[10*13+10]; mf[19] = mb[10*13+11]; mf[20] = mb[10*13+12];
            mf[21] = mb[11*13+11]; mf[22] = mb[11*13+12]; mf[23] = mb[12*13+12];
        } else {
            // rot-trans blocks i=1 (9), i=2 (9)
            #pragma unroll
            for (int r = 0; r < 3; ++r)
                #pragma unroll
                for (int c = 0; c < 3; ++c) mf[r*3 + c] = mb[(3 + r)*13 + 10 + c];
            #pragma unroll
            for (int r = 0; r < 3; ++r)
                #pragma unroll
                for (int c = 0; c < 3; ++c) mf[9 + r*3 + c] = mb[(6 + r)*13 + 10 + c];
        }
    }
    __syncthreads();  // done with sbuf; red may now be written

    // ---- per-problem pose (rows 0..2; bottom row stays (0,0,0,1)) ----
    double t[3][4];
    {
        const float* tp = Tg + (long long)prob * 16;
        #pragma unroll
        for (int i = 0; i < 3; ++i)
            #pragma unroll
            for (int j = 0; j < 4; ++j)
                t[i][j] = (double)tp[i * 4 + j];
    }

    double q[28];  // full 7x7 upper triangle (assembled post-reduction)

    #pragma unroll 1
    for (int it = 0; it < 5; ++it) {
        // partial accumulator: [0..12] = y6, [13+OI6(k,l)] = Omega(k,l), k<=l<6
        double part[34];
        #pragma unroll
        for (int j = 0; j < 34; ++j) part[j] = 0.0;

        // ---- role builders (wave-uniform branch; no divergence) ----
        auto diagBlk = [&](int i, const float* g) {
            double md[3][3];
            md[0][0] = (double)g[0]; md[0][1] = (double)g[1]; md[0][2] = (double)g[2];
            md[1][0] = md[0][1];     md[1][1] = (double)g[3]; md[1][2] = (double)g[4];
            md[2][0] = md[0][2];     md[2][1] = md[1][2];     md[2][2] = (double)g[5];
            const double jx = t[i][0], jy = t[i][1], jz = t[i][2];
            #pragma unroll
            for (int r = 0; r < 3; ++r)
                part[3*i + r] += md[r][0]*jx + md[r][1]*jy + md[r][2]*jz;
            double X[3][3], Z[3][3];
            #pragma unroll
            for (int r = 0; r < 3; ++r) {
                X[r][0] = md[r][1]*jz - md[r][2]*jy;
                X[r][1] = md[r][2]*jx - md[r][0]*jz;
                X[r][2] = md[r][0]*jy - md[r][1]*jx;
            }
            #pragma unroll
            for (int l = 0; l < 3; ++l) {
                Z[0][l] = X[1][l]*jz - X[2][l]*jy;
                Z[1][l] = X[2][l]*jx - X[0][l]*jz;
                Z[2][l] = X[0][l]*jy - X[1][l]*jx;
            }
            #pragma unroll
            for (int k = 0; k < 3; ++k)
                #pragma unroll
                for (int l = k; l < 3; ++l) part[13 + OI6(k, l)] += Z[k][l];
        };
        auto offBlk = [&](int i, int j, const float* g) {
            double md[3][3];
            #pragma unroll
            for (int r = 0; r < 3; ++r)
                #pragma unroll
                for (int c = 0; c < 3; ++c) md[r][c] = (double)g[r*3 + c];
            const double jx = t[j][0], jy = t[j][1], jz = t[j][2];
            const double ix = t[i][0], iy = t[i][1], iz = t[i][2];
            #pragma unroll
            for (int r = 0; r < 3; ++r)
                part[3*i + r] += md[r][0]*jx + md[r][1]*jy + md[r][2]*jz;
            #pragma unroll
            for (int c = 0; c < 3; ++c)
                part[3*j + c] += md[0][c]*ix + md[1][c]*iy + md[2][c]*iz;
            double X[3][3], Z[3][3];
            #pragma unroll
            for (int r = 0; r < 3; ++r) {
                X[r][0] = md[r][1]*jz - md[r][2]*jy;
                X[r][1] = md[r][2]*jx - md[r][0]*jz;
                X[r][2] = md[r][0]*jy - md[r][1]*jx;
            }
            #pragma unroll
            for (int l = 0; l < 3; ++l) {
                Z[0][l] = X[1][l]*iz - X[2][l]*iy;
                Z[1][l] = X[2][l]*ix - X[0][l]*iz;
                Z[2][l] = X[0][l]*iy - X[1][l]*ix;
            }
            #pragma unroll
            for (int k = 0; k < 3; ++k)
                #pragma unroll
                for (int l = k; l < 3; ++l) part[13 + OI6(k, l)] += Z[k][l] + Z[l][k];
        };
        auto p2Blk = [&](int i, const float* g) {
            double md[3][3];
            #pragma unroll
            for (int r = 0; r < 3; ++r)
                #pragma unroll
                for (int c = 0; c < 3; ++c) md[r][c] = (double)g[r*3 + c];
            const double ix = t[i][0], iy = t[i][1], iz = t[i][2];
            #pragma unroll
            for (int r = 0; r < 3; ++r)
                part[3*i + r] += md[r][0]*t[0][3] + md[r][1]*t[1][3] + md[r][2]*t[2][3];
            #pragma unroll
            for (int c = 0; c < 3; ++c)
                part[10 + c] += md[0][c]*ix + md[1][c]*iy + md[2][c]*iz;
            double W[3][3];
            #pragma unroll
            for (int r = 0; r < 3; ++r)
                #pragma unroll
                for (int c = 0; c < 3; ++c)
                    W[r][c] = md[r][0]*t[0][c] + md[r][1]*t[1][c] + md[r][2]*t[2][c];
            #pragma unroll
            for (int c = 0; c < 3; ++c) {
                part[13 + OI6(0, 3 + c)] += W[1][c]*iz - W[2][c]*iy;
                part[13 + OI6(1, 3 + c)] += W[2][c]*ix - W[0][c]*iz;
                part[13 + OI6(2, 3 + c)] += W[0][c]*iy - W[1][c]*ix;
            }
        };

        if (wv == 0) {
            diagBlk(0, mf + 0);
            diagBlk(1, mf + 6);
            offBlk(0, 1, mf + 12);
        } else if (wv == 1) {
            diagBlk(2, mf + 0);
            offBlk(0, 2, mf + 6);
            // ones row (row/col 9)
            #pragma unroll
            for (int r = 0; r < 9; ++r) {
                const double m = (double)mf[15 + r];
                part[r] += m;
                part[9] += m * t[r / 3][r % 3];
            }
            part[9] += (double)mf[24];
            #pragma unroll
            for (int s = 0; s < 3; ++s) {
                const double m = (double)mf[25 + s];
                part[9] += m * t[s][3];
                part[10 + s] += m;
            }
        } else if (wv == 2) {
            offBlk(1, 2, mf + 0);
            p2Blk(0, mf + 9);
            // trans-trans Mtt
            double mt[3][3];
            mt[0][0] = (double)mf[18]; mt[0][1] = (double)mf[19]; mt[0][2] = (double)mf[20];
            mt[1][0] = mt[0][1];       mt[1][1] = (double)mf[21]; mt[1][2] = (double)mf[22];
            mt[2][0] = mt[0][2];       mt[2][1] = mt[1][2];       mt[2][2] = (double)mf[23];
            #pragma unroll
            for (int r = 0; r < 3; ++r)
                part[10 + r] += mt[r][0]*t[0][3] + mt[r][1]*t[1][3] + mt[r][2]*t[2][3];
            double wb[3][3];
            #pragma unroll
            for (int r = 0; r < 3; ++r)
                #pragma unroll
                for (int c = 0; c < 3; ++c)
                    wb[r][c] = mt[r][0]*t[0][c] + mt[r][1]*t[1][c] + mt[r][2]*t[2][c];
            #pragma unroll
            for (int k = 0; k < 3; ++k)
                #pragma unroll
                for (int l = k; l < 3; ++l)
                    part[13 + OI6(3 + k, 3 + l)] += t[0][k]*wb[0][l] + t[1][k]*wb[1][l] + t[2][k]*wb[2][l];
        } else {
            p2Blk(1, mf + 0);
            p2Blk(2, mf + 9);
        }

        // ---- two-phase LDS reduction (17 slots each; fixed sum order) ----
        double tot[34];
        #pragma unroll
        for (int j = 0; j < 17; ++j) red[(j * 4 + wv) * 64 + lane] = part[j];
        __syncthreads();
        #pragma unroll
        for (int j = 0; j < 17; ++j)
            tot[j] = (red[(j*4+0)*64+lane] + red[(j*4+1)*64+lane])
                   + (red[(j*4+2)*64+lane] + red[(j*4+3)*64+lane]);
        __syncthreads();
        #pragma unroll
        for (int j = 0; j < 17; ++j) red[(j * 4 + wv) * 64 + lane] = part[17 + j];
        __syncthreads();
        #pragma unroll
        for (int j = 0; j < 17; ++j)
            tot[17 + j] = (red[(j*4+0)*64+lane] + red[(j*4+1)*64+lane])
                        + (red[(j*4+2)*64+lane] + red[(j*4+3)*64+lane]);
        __syncthreads();

        // ---- unpack + phase5 (redundant per wave, bit-identical) ----
        double y6[13];
        #pragma unroll
        for (int j = 0; j < 13; ++j) y6[j] = tot[j];
        #pragma unroll
        for (int k = 0; k < 6; ++k)
            #pragma unroll
            for (int l = k; l < 6; ++l) q[QI(k, l)] = tot[13 + OI6(k, l)];
        {
            double q66 = y6[9];
            #pragma unroll
            for (int i = 0; i < 3; ++i) {
                q66 += t[i][0]*y6[3*i+0] + t[i][1]*y6[3*i+1] + t[i][2]*y6[3*i+2];
                q66 += t[i][3]*y6[10 + i];
            }
            q[QI(6, 6)] = q66;
            double qa0 = 0.0, qa1 = 0.0, qa2 = 0.0;
            #pragma unroll
            for (int i = 0; i < 3; ++i) {
                const double v0 = y6[3*i+0], v1 = y6[3*i+1], v2 = y6[3*i+2];
                qa0 += v1*t[i][2] - v2*t[i][1];
                qa1 += v2*t[i][0] - v0*t[i][2];
                qa2 += v0*t[i][1] - v1*t[i][0];
            }
            q[QI(0, 6)] = qa0; q[QI(1, 6)] = qa1; q[QI(2, 6)] = qa2;
            #pragma unroll
            for (int k = 0; k < 3; ++k)
                q[QI(3 + k, 6)] = t[0][k]*y6[10] + t[1][k]*y6[11] + t[2][k]*y6[12];
        }

        // ---- regularization (reference-exact) ----
        const double trQ  = q[QI(3, 3)] + q[QI(4, 4)] + q[QI(5, 5)];
        const double regT = 1e-8 * fmax(trQ, 1.0);
        q[QI(0, 0)] += 10.0;
        q[QI(1, 1)] += 10.0;
        q[QI(2, 2)] += 10.0;
        q[QI(3, 3)] += regT;
        q[QI(4, 4)] += regT;
        q[QI(5, 5)] += regT;

        // ---- 1e-5*(1+max(Omega)) via fmax tree (fmax exact => any order) ----
        double e[21];
        #pragma unroll
        for (int k = 0; k < 6; ++k)
            #pragma unroll
            for (int l = k; l < 6; ++l) e[OI6(k, l)] = q[QI(k, l)];
        double u[11];
        #pragma unroll
        for (int i = 0; i < 10; ++i) u[i] = fmax(e[i], e[i + 10]);
        u[10] = e[20];
        double v5[6];
        #pragma unroll
        for (int i = 0; i < 5; ++i) v5[i] = fmax(u[i], u[i + 5]);
        v5[5] = u[10];
        const double mx = fmax(fmax(fmax(v5[0], v5[3]), fmax(v5[1], v5[4])), fmax(v5[2], v5[5]));
        const double reg2 = 1e-5 * (1.0 + mx);

        // ---- solve (Omega + reg2*I) x = g,  v = -x (symmetric GE, SPD) ----
        double w[21], bb[6], dinv[6];
        #pragma unroll
        for (int k = 0; k < 6; ++k) {
            #pragma unroll
            for (int l = k; l < 6; ++l) w[OI6(k, l)] = q[QI(k, l)];
            w[OI6(k, k)] += reg2;
            bb[k] = q[QI(k, 6)];
        }
        #pragma unroll
        for (int k = 0; k < 6; ++k) {
            const double inv = 1.0 / w[OI6(k, k)];
            dinv[k] = inv;
            #pragma unroll
            for (int i = k + 1; i < 6; ++i) {
                const double f = w[OI6(k, i)] * inv;
                #pragma unroll
                for (int j = i; j < 6; ++j) w[OI6(i, j)] -= f * w[OI6(k, j)];
                bb[i] -= f * bb[k];
            }
        }
        double x[6];
        #pragma unroll
        for (int i = 5; i >= 0; --i) {
            double s = bb[i];
            #pragma unroll
            for (int j = i + 1; j < 6; ++j) s -= w[OI6(i, j)] * x[j];
            x[i] = s * dinv[i];
        }
        const double wx = -x[0], wy = -x[1], wz = -x[2];
        const double ux = -x[3], uy = -x[4], uz = -x[5];

        // ---- closed-form expm of se(3): E = [[R, V*u],[0,1]] ----
        const double tsq = wx*wx + wy*wy + wz*wz;
        double A, B, Cc;
        if (tsq < 1.0) {
            A  = 1.0 + tsq * (-1.0/6 + tsq * (1.0/120 + tsq * (-1.0/5040 + tsq * (1.0/362880
                 + tsq * (-1.0/39916800.0 + tsq * (1.0/6227020800.0 + tsq * (-1.0/1307674368000.0
                 + tsq * (1.0/355687428096000.0))))))));
            B  = 0.5 + tsq * (-1.0/24 + tsq * (1.0/720 + tsq * (-1.0/40320 + tsq * (1.0/3628800
                 + tsq * (-1.0/479001600.0 + tsq * (1.0/87178291200.0 + tsq * (-1.0/20922789888000.0
                 + tsq * (1.0/6402373705728000.0))))))));
            Cc = 1.0/6 + tsq * (-1.0/120 + tsq * (1.0/5040 + tsq * (-1.0/362880 + tsq * (1.0/39916800.0
                 + tsq * (-1.0/6227020800.0 + tsq * (1.0/1307674368000.0 + tsq * (-1.0/355687428096000.0
                 + tsq * (1.0/121645100408832000.0))))))));
        } else {
            const double th = sqrt(tsq);
            const double s = sin(th), c = cos(th);
            A  = s / th;
            B  = (1.0 - c) / tsq;
            Cc = (th - s) / (tsq * th);
        }
        const double K2xx = wx*wx - tsq, K2yy = wy*wy - tsq, K2zz = wz*wz - tsq;
        const double K2xy = wx*wy, K2xz = wx*wz, K2yz = wy*wz;
        double R[3][3];
        R[0][0] = 1.0 + B*K2xx;     R[0][1] = -A*wz + B*K2xy;  R[0][2] =  A*wy + B*K2xz;
        R[1][0] =  A*wz + B*K2xy;   R[1][1] = 1.0 + B*K2yy;    R[1][2] = -A*wx + B*K2yz;
        R[2][0] = -A*wy + B*K2xz;   R[2][1] =  A*wx + B*K2yz;  R[2][2] = 1.0 + B*K2zz;
        const double V00 = 1.0 + Cc*K2xx,    V01 = -B*wz + Cc*K2xy, V02 =  B*wy + Cc*K2xz;
        const double V10 =  B*wz + Cc*K2xy,  V11 = 1.0 + Cc*K2yy,   V12 = -B*wx + Cc*K2yz;
        const double V20 = -B*wy + Cc*K2xz,  V21 =  B*wx + Cc*K2yz, V22 = 1.0 + Cc*K2zz;
        const double ex = V00*ux + V01*uy + V02*uz;
        const double ey = V10*ux + V11*uy + V12*uz;
        const double ez = V20*ux + V21*uy + V22*uz;

        // ---- T = T @ E ----
        #pragma unroll
        for (int i = 0; i < 3; ++i) {
            const double a0 = t[i][0], a1 = t[i][1], a2 = t[i][2], a3 = t[i][3];
            t[i][0] = a0*R[0][0] + a1*R[1][0] + a2*R[2][0];
            t[i][1] = a0*R[0][1] + a1*R[1][1] + a2*R[2][1];
            t[i][2] = a0*R[0][2] + a1*R[1][2] + a2*R[2][2];
            t[i][3] = a0*ex + a1*ey + a2*ez + a3;
        }
    }

    // ---- outputs, role-split: wv0 -> T (16 f), wv1..3 -> 12 Omega f each ----
    if (wv == 0) {
        float* to = outg + (long long)prob * 16;
        #pragma unroll
        for (int i = 0; i < 3; ++i)
            #pragma unroll
            for (int j = 0; j < 4; ++j)
                to[i * 4 + j] = (float)t[i][j];
        to[12] = 0.0f; to[13] = 0.0f; to[14] = 0.0f; to[15] = 1.0f;
    } else {
        const double invden = 1.0 / (t[2][3] * t[2][3] + 1e-8);
        float* oo = outg + (long long)NPROB * 16 + (long long)prob * 36 + 12 * (wv - 1);
        #pragma unroll
        for (int e2 = 0; e2 < 12; ++e2) {
            const int k = (12 * (wv - 1) + e2) / 6;
            const int l = (12 * (wv - 1) + e2) % 6;
            oo[e2] = (float)(q[(k <= l) ? QI(k, l) : QI(l, k)] * invden);
        }
    }
}

extern "C" void kernel_launch(void* const* d_in, const int* in_sizes, int n_in,
                              void* d_out, int out_size, void* d_ws, size_t ws_size,
                              hipStream_t stream) {
    const float* Mg = (const float*)d_in[0];  // [64,2048,13,13] fp32
    const float* Tg = (const float*)d_in[1];  // [64,2048,4,4]  fp32
    float* out = (float*)d_out;               // [NPROB*16 + NPROB*36] fp32
    (void)in_sizes; (void)n_in; (void)out_size; (void)d_ws; (void)ws_size;

    const int threads = 256;               // 4 waves, all on the same 64 problems
    const int blocks  = NPROB / 64;        // 2048
    gn5_kernel<<<blocks, threads, 0, stream>>>(Mg, Tg, out);
}

// Round 5
// 288.108 us; speedup vs baseline: 1.0095x; 1.0095x over previous
//
#include <hip/hip_runtime.h>
#include <math.h>

#define NPROB (64 * 2048)

__host__ __device__ constexpr int OI6(int i, int j) { return i * 6 - i * (i - 1) / 2 + (j - i); }
__host__ __device__ constexpr int QI(int i, int j)  { return i * 7 - i * (i - 1) / 2 + (j - i); }

// 4 waves per block, all mirroring the same 64 problems (one per lane).
// Wave r builds role-r partials of {y6[13], Omega-upper[21]}; two-phase LDS
// reduction; every wave redundantly runs the serial solve/expm/update
// (bit-identical: fixed summation order). ALL per-thread arrays are accessed
// with compile-time indices only (dynamic indexing -> scratch, the round-4 bug).
__global__ __launch_bounds__(256) void gn5_kernel(const float* __restrict__ Mg,
                                                  const float* __restrict__ Tg,
                                                  float* __restrict__ outg) {
    const int tid  = threadIdx.x;
    const int lane = tid & 63;
    const int wv   = tid >> 6;
    const int prob = blockIdx.x * 64 + lane;

    // LDS: staging view (64*169 fp32 = 43264 B) unioned with the reduction
    // view (17 slots * 4 roles * 64 lanes fp64 = 34816 B).
    __shared__ __align__(16) unsigned char smem[64 * 169 * 4];
    float*  sbuf = (float*)smem;
    double* red  = (double*)smem;

    // ---- stage M for this block's 64 problems (coalesced float4) ----
    {
        const float4* src = (const float4*)(Mg + (long long)blockIdx.x * (64 * 169));
        float4* dst = (float4*)smem;
        #pragma unroll 1
        for (int i = tid; i < (64 * 169) / 4; i += 256) dst[i] = src[i];
    }
    __syncthreads();

    // ---- role-specific M extraction (each lane keeps <=28 fp32) ----
    float mf[28];
    {
        const float* mb = sbuf + lane * 169;
        if (wv == 0) {
            mf[0] = mb[0*13+0]; mf[1] = mb[0*13+1]; mf[2] = mb[0*13+2];
            mf[3] = mb[1*13+1]; mf[4] = mb[1*13+2]; mf[5] = mb[2*13+2];
            mf[6] = mb[3*13+3]; mf[7] = mb[3*13+4]; mf[8] = mb[3*13+5];
            mf[9] = mb[4*13+4]; mf[10] = mb[4*13+5]; mf[11] = mb[5*13+5];
            #pragma unroll
            for (int r = 0; r < 3; ++r)
                #pragma unroll
                for (int c = 0; c < 3; ++c) mf[12 + r*3 + c] = mb[r*13 + 3 + c];
        } else if (wv == 1) {
            mf[0] = mb[6*13+6]; mf[1] = mb[6*13+7]; mf[2] = mb[6*13+8];
            mf[3] = mb[7*13+7]; mf[4] = mb[7*13+8]; mf[5] = mb[8*13+8];
            #pragma unroll
            for (int r = 0; r < 3; ++r)
                #pragma unroll
                for (int c = 0; c < 3; ++c) mf[6 + r*3 + c] = mb[r*13 + 6 + c];
            #pragma unroll
            for (int r = 0; r < 9; ++r) mf[15 + r] = mb[r*13 + 9];
            mf[24] = mb[9*13 + 9];
            #pragma unroll
            for (int s = 0; s < 3; ++s) mf[25 + s] = mb[9*13 + 10 + s];
        } else if (wv == 2) {
            #pragma unroll
            for (int r = 0; r < 3; ++r)
                #pragma unroll
                for (int c = 0; c < 3; ++c) mf[r*3 + c] = mb[(3 + r)*13 + 6 + c];
            #pragma unroll
            for (int r = 0; r < 3; ++r)
                #pragma unroll
                for (int c = 0; c < 3; ++c) mf[9 + r*3 + c] = mb[r*13 + 10 + c];
            mf[18] = mb[10*13+10]; mf[19] = mb[10*13+11]; mf[20] = mb[10*13+12];
            mf[21] = mb[11*13+11]; mf[22] = mb[11*13+12]; mf[23] = mb[12*13+12];
        } else {
            #pragma unroll
            for (int r = 0; r < 3; ++r)
                #pragma unroll
                for (int c = 0; c < 3; ++c) mf[r*3 + c] = mb[(3 + r)*13 + 10 + c];
            #pragma unroll
            for (int r = 0; r < 3; ++r)
                #pragma unroll
                for (int c = 0; c < 3; ++c) mf[9 + r*3 + c] = mb[(6 + r)*13 + 10 + c];
        }
    }
    __syncthreads();  // done with sbuf; red may now be written

    // ---- per-problem pose (rows 0..2; bottom row stays (0,0,0,1)) ----
    double t[3][4];
    {
        const float* tp = Tg + (long long)prob * 16;
        #pragma unroll
        for (int i = 0; i < 3; ++i)
            #pragma unroll
            for (int j = 0; j < 4; ++j)
                t[i][j] = (double)tp[i * 4 + j];
    }

    double q[28];  // full 7x7 upper triangle (assembled post-reduction)

    #pragma unroll 1
    for (int it = 0; it < 5; ++it) {
        // partial accumulator: [0..12] = y6, [13+OI6(k,l)] = Omega(k,l), k<=l<6
        double part[34];
        #pragma unroll
        for (int j = 0; j < 34; ++j) part[j] = 0.0;

        auto diagBlk = [&](int i, const float* g) {
            double md[3][3];
            md[0][0] = (double)g[0]; md[0][1] = (double)g[1]; md[0][2] = (double)g[2];
            md[1][0] = md[0][1];     md[1][1] = (double)g[3]; md[1][2] = (double)g[4];
            md[2][0] = md[0][2];     md[2][1] = md[1][2];     md[2][2] = (double)g[5];
            const double jx = t[i][0], jy = t[i][1], jz = t[i][2];
            #pragma unroll
            for (int r = 0; r < 3; ++r)
                part[3*i + r] += md[r][0]*jx + md[r][1]*jy + md[r][2]*jz;
            double X[3][3], Z[3][3];
            #pragma unroll
            for (int r = 0; r < 3; ++r) {
                X[r][0] = md[r][1]*jz - md[r][2]*jy;
                X[r][1] = md[r][2]*jx - md[r][0]*jz;
                X[r][2] = md[r][0]*jy - md[r][1]*jx;
            }
            #pragma unroll
            for (int l = 0; l < 3; ++l) {
                Z[0][l] = X[1][l]*jz - X[2][l]*jy;
                Z[1][l] = X[2][l]*jx - X[0][l]*jz;
                Z[2][l] = X[0][l]*jy - X[1][l]*jx;
            }
            #pragma unroll
            for (int k = 0; k < 3; ++k)
                #pragma unroll
                for (int l = k; l < 3; ++l) part[13 + OI6(k, l)] += Z[k][l];
        };
        auto offBlk = [&](int i, int j, const float* g) {
            double md[3][3];
            #pragma unroll
            for (int r = 0; r < 3; ++r)
                #pragma unroll
                for (int c = 0; c < 3; ++c) md[r][c] = (double)g[r*3 + c];
            const double jx = t[j][0], jy = t[j][1], jz = t[j][2];
            const double ix = t[i][0], iy = t[i][1], iz = t[i][2];
            #pragma unroll
            for (int r = 0; r < 3; ++r)
                part[3*i + r] += md[r][0]*jx + md[r][1]*jy + md[r][2]*jz;
            #pragma unroll
            for (int c = 0; c < 3; ++c)
                part[3*j + c] += md[0][c]*ix + md[1][c]*iy + md[2][c]*iz;
            double X[3][3], Z[3][3];
            #pragma unroll
            for (int r = 0; r < 3; ++r) {
                X[r][0] = md[r][1]*jz - md[r][2]*jy;
                X[r][1] = md[r][2]*jx - md[r][0]*jz;
                X[r][2] = md[r][0]*jy - md[r][1]*jx;
            }
            #pragma unroll
            for (int l = 0; l < 3; ++l) {
                Z[0][l] = X[1][l]*iz - X[2][l]*iy;
                Z[1][l] = X[2][l]*ix - X[0][l]*iz;
                Z[2][l] = X[0][l]*iy - X[1][l]*ix;
            }
            #pragma unroll
            for (int k = 0; k < 3; ++k)
                #pragma unroll
                for (int l = k; l < 3; ++l) part[13 + OI6(k, l)] += Z[k][l] + Z[l][k];
        };
        auto p2Blk = [&](int i, const float* g) {
            double md[3][3];
            #pragma unroll
            for (int r = 0; r < 3; ++r)
                #pragma unroll
                for (int c = 0; c < 3; ++c) md[r][c] = (double)g[r*3 + c];
            const double ix = t[i][0], iy = t[i][1], iz = t[i][2];
            #pragma unroll
            for (int r = 0; r < 3; ++r)
                part[3*i + r] += md[r][0]*t[0][3] + md[r][1]*t[1][3] + md[r][2]*t[2][3];
            #pragma unroll
            for (int c = 0; c < 3; ++c)
                part[10 + c] += md[0][c]*ix + md[1][c]*iy + md[2][c]*iz;
            double W[3][3];
            #pragma unroll
            for (int r = 0; r < 3; ++r)
                #pragma unroll
                for (int c = 0; c < 3; ++c)
                    W[r][c] = md[r][0]*t[0][c] + md[r][1]*t[1][c] + md[r][2]*t[2][c];
            #pragma unroll
            for (int c = 0; c < 3; ++c) {
                part[13 + OI6(0, 3 + c)] += W[1][c]*iz - W[2][c]*iy;
                part[13 + OI6(1, 3 + c)] += W[2][c]*ix - W[0][c]*iz;
                part[13 + OI6(2, 3 + c)] += W[0][c]*iy - W[1][c]*ix;
            }
        };

        if (wv == 0) {
            diagBlk(0, mf + 0);
            diagBlk(1, mf + 6);
            offBlk(0, 1, mf + 12);
        } else if (wv == 1) {
            diagBlk(2, mf + 0);
            offBlk(0, 2, mf + 6);
            #pragma unroll
            for (int r = 0; r < 9; ++r) {
                const double m = (double)mf[15 + r];
                part[r] += m;
                part[9] += m * t[r / 3][r % 3];
            }
            part[9] += (double)mf[24];
            #pragma unroll
            for (int s = 0; s < 3; ++s) {
                const double m = (double)mf[25 + s];
                part[9] += m * t[s][3];
                part[10 + s] += m;
            }
        } else if (wv == 2) {
            offBlk(1, 2, mf + 0);
            p2Blk(0, mf + 9);
            double mt[3][3];
            mt[0][0] = (double)mf[18]; mt[0][1] = (double)mf[19]; mt[0][2] = (double)mf[20];
            mt[1][0] = mt[0][1];       mt[1][1] = (double)mf[21]; mt[1][2] = (double)mf[22];
            mt[2][0] = mt[0][2];       mt[2][1] = mt[1][2];       mt[2][2] = (double)mf[23];
            #pragma unroll
            for (int r = 0; r < 3; ++r)
                part[10 + r] += mt[r][0]*t[0][3] + mt[r][1]*t[1][3] + mt[r][2]*t[2][3];
            double wb[3][3];
            #pragma unroll
            for (int r = 0; r < 3; ++r)
                #pragma unroll
                for (int c = 0; c < 3; ++c)
                    wb[r][c] = mt[r][0]*t[0][c] + mt[r][1]*t[1][c] + mt[r][2]*t[2][c];
            #pragma unroll
            for (int k = 0; k < 3; ++k)
                #pragma unroll
                for (int l = k; l < 3; ++l)
                    part[13 + OI6(3 + k, 3 + l)] += t[0][k]*wb[0][l] + t[1][k]*wb[1][l] + t[2][k]*wb[2][l];
        } else {
            p2Blk(1, mf + 0);
            p2Blk(2, mf + 9);
        }

        // ---- two-phase LDS reduction (17 slots each; fixed sum order) ----
        double tot[34];
        #pragma unroll
        for (int j = 0; j < 17; ++j) red[(j * 4 + wv) * 64 + lane] = part[j];
        __syncthreads();
        #pragma unroll
        for (int j = 0; j < 17; ++j)
            tot[j] = (red[(j*4+0)*64+lane] + red[(j*4+1)*64+lane])
                   + (red[(j*4+2)*64+lane] + red[(j*4+3)*64+lane]);
        __syncthreads();
        #pragma unroll
        for (int j = 0; j < 17; ++j) red[(j * 4 + wv) * 64 + lane] = part[17 + j];
        __syncthreads();
        #pragma unroll
        for (int j = 0; j < 17; ++j)
            tot[17 + j] = (red[(j*4+0)*64+lane] + red[(j*4+1)*64+lane])
                        + (red[(j*4+2)*64+lane] + red[(j*4+3)*64+lane]);
        __syncthreads();

        // ---- unpack + last column of Q (redundant per wave, bit-identical) ----
        double y6[13];
        #pragma unroll
        for (int j = 0; j < 13; ++j) y6[j] = tot[j];
        #pragma unroll
        for (int k = 0; k < 6; ++k)
            #pragma unroll
            for (int l = k; l < 6; ++l) q[QI(k, l)] = tot[13 + OI6(k, l)];
        {
            double q66 = y6[9];
            #pragma unroll
            for (int i = 0; i < 3; ++i) {
                q66 += t[i][0]*y6[3*i+0] + t[i][1]*y6[3*i+1] + t[i][2]*y6[3*i+2];
                q66 += t[i][3]*y6[10 + i];
            }
            q[QI(6, 6)] = q66;
            double qa0 = 0.0, qa1 = 0.0, qa2 = 0.0;
            #pragma unroll
            for (int i = 0; i < 3; ++i) {
                const double v0 = y6[3*i+0], v1 = y6[3*i+1], v2 = y6[3*i+2];
                qa0 += v1*t[i][2] - v2*t[i][1];
                qa1 += v2*t[i][0] - v0*t[i][2];
                qa2 += v0*t[i][1] - v1*t[i][0];
            }
            q[QI(0, 6)] = qa0; q[QI(1, 6)] = qa1; q[QI(2, 6)] = qa2;
            #pragma unroll
            for (int k = 0; k < 3; ++k)
                q[QI(3 + k, 6)] = t[0][k]*y6[10] + t[1][k]*y6[11] + t[2][k]*y6[12];
        }

        // ---- regularization (reference-exact) ----
        const double trQ  = q[QI(3, 3)] + q[QI(4, 4)] + q[QI(5, 5)];
        const double regT = 1e-8 * fmax(trQ, 1.0);
        q[QI(0, 0)] += 10.0;
        q[QI(1, 1)] += 10.0;
        q[QI(2, 2)] += 10.0;
        q[QI(3, 3)] += regT;
        q[QI(4, 4)] += regT;
        q[QI(5, 5)] += regT;

        // ---- 1e-5*(1+max(Omega)) via fmax tree (fmax exact => any order) ----
        double e[21];
        #pragma unroll
        for (int k = 0; k < 6; ++k)
            #pragma unroll
            for (int l = k; l < 6; ++l) e[OI6(k, l)] = q[QI(k, l)];
        double u[11];
        #pragma unroll
        for (int i = 0; i < 10; ++i) u[i] = fmax(e[i], e[i + 10]);
        u[10] = e[20];
        double v5[6];
        #pragma unroll
        for (int i = 0; i < 5; ++i) v5[i] = fmax(u[i], u[i + 5]);
        v5[5] = u[10];
        const double mx = fmax(fmax(fmax(v5[0], v5[3]), fmax(v5[1], v5[4])), fmax(v5[2], v5[5]));
        const double reg2 = 1e-5 * (1.0 + mx);

        // ---- solve (Omega + reg2*I) x = g,  v = -x (symmetric GE, SPD) ----
        double w[21], bb[6], dinv[6];
        #pragma unroll
        for (int k = 0; k < 6; ++k) {
            #pragma unroll
            for (int l = k; l < 6; ++l) w[OI6(k, l)] = q[QI(k, l)];
            w[OI6(k, k)] += reg2;
            bb[k] = q[QI(k, 6)];
        }
        #pragma unroll
        for (int k = 0; k < 6; ++k) {
            const double inv = 1.0 / w[OI6(k, k)];
            dinv[k] = inv;
            #pragma unroll
            for (int i = k + 1; i < 6; ++i) {
                const double f = w[OI6(k, i)] * inv;
                #pragma unroll
                for (int j = i; j < 6; ++j) w[OI6(i, j)] -= f * w[OI6(k, j)];
                bb[i] -= f * bb[k];
            }
        }
        double x[6];
        #pragma unroll
        for (int i = 5; i >= 0; --i) {
            double s = bb[i];
            #pragma unroll
            for (int j = i + 1; j < 6; ++j) s -= w[OI6(i, j)] * x[j];
            x[i] = s * dinv[i];
        }
        const double wx = -x[0], wy = -x[1], wz = -x[2];
        const double ux = -x[3], uy = -x[4], uz = -x[5];

        // ---- closed-form expm of se(3): E = [[R, V*u],[0,1]] ----
        const double tsq = wx*wx + wy*wy + wz*wz;
        double A, B, Cc;
        if (tsq < 1.0) {
            A  = 1.0 + tsq * (-1.0/6 + tsq * (1.0/120 + tsq * (-1.0/5040 + tsq * (1.0/362880
                 + tsq * (-1.0/39916800.0 + tsq * (1.0/6227020800.0 + tsq * (-1.0/1307674368000.0
                 + tsq * (1.0/355687428096000.0))))))));
            B  = 0.5 + tsq * (-1.0/24 + tsq * (1.0/720 + tsq * (-1.0/40320 + tsq * (1.0/3628800
                 + tsq * (-1.0/479001600.0 + tsq * (1.0/87178291200.0 + tsq * (-1.0/20922789888000.0
                 + tsq * (1.0/6402373705728000.0))))))));
            Cc = 1.0/6 + tsq * (-1.0/120 + tsq * (1.0/5040 + tsq * (-1.0/362880 + tsq * (1.0/39916800.0
                 + tsq * (-1.0/6227020800.0 + tsq * (1.0/1307674368000.0 + tsq * (-1.0/355687428096000.0
                 + tsq * (1.0/121645100408832000.0))))))));
        } else {
            const double th = sqrt(tsq);
            const double s = sin(th), c = cos(th);
            A  = s / th;
            B  = (1.0 - c) / tsq;
            Cc = (th - s) / (tsq * th);
        }
        const double K2xx = wx*wx - tsq, K2yy = wy*wy - tsq, K2zz = wz*wz - tsq;
        const double K2xy = wx*wy, K2xz = wx*wz, K2yz = wy*wz;
        double R[3][3];
        R[0][0] = 1.0 + B*K2xx;     R[0][1] = -A*wz + B*K2xy;  R[0][2] =  A*wy + B*K2xz;
        R[1][0] =  A*wz + B*K2xy;   R[1][1] = 1.0 + B*K2yy;    R[1][2] = -A*wx + B*K2yz;
        R[2][0] = -A*wy + B*K2xz;   R[2][1] =  A*wx + B*K2yz;  R[2][2] = 1.0 + B*K2zz;
        const double V00 = 1.0 + Cc*K2xx,    V01 = -B*wz + Cc*K2xy, V02 =  B*wy + Cc*K2xz;
        const double V10 =  B*wz + Cc*K2xy,  V11 = 1.0 + Cc*K2yy,   V12 = -B*wx + Cc*K2yz;
        const double V20 = -B*wy + Cc*K2xz,  V21 =  B*wx + Cc*K2yz, V22 = 1.0 + Cc*K2zz;
        const double ex = V00*ux + V01*uy + V02*uz;
        const double ey = V10*ux + V11*uy + V12*uz;
        const double ez = V20*ux + V21*uy + V22*uz;

        // ---- T = T @ E ----
        #pragma unroll
        for (int i = 0; i < 3; ++i) {
            const double a0 = t[i][0], a1 = t[i][1], a2 = t[i][2], a3 = t[i][3];
            t[i][0] = a0*R[0][0] + a1*R[1][0] + a2*R[2][0];
            t[i][1] = a0*R[0][1] + a1*R[1][1] + a2*R[2][1];
            t[i][2] = a0*R[0][2] + a1*R[1][2] + a2*R[2][2];
            t[i][3] = a0*ex + a1*ey + a2*ez + a3;
        }
    }

    // ---- outputs, role-split with COMPILE-TIME q indices per branch ----
    if (wv == 0) {
        float* to = outg + (long long)prob * 16;
        #pragma unroll
        for (int i = 0; i < 3; ++i)
            #pragma unroll
            for (int j = 0; j < 4; ++j)
                to[i * 4 + j] = (float)t[i][j];
        to[12] = 0.0f; to[13] = 0.0f; to[14] = 0.0f; to[15] = 1.0f;
    } else {
        const double invden = 1.0 / (t[2][3] * t[2][3] + 1e-8);
        float* oo = outg + (long long)NPROB * 16 + (long long)prob * 36;
        if (wv == 1) {
            #pragma unroll
            for (int l = 0; l < 6; ++l) oo[l]      = (float)(q[QI(0, l)] * invden);
            #pragma unroll
            for (int l = 0; l < 6; ++l) oo[6 + l]  = (float)(q[(1 <= l) ? QI(1, l) : QI(l, 1)] * invden);
        } else if (wv == 2) {
            #pragma unroll
            for (int l = 0; l < 6; ++l) oo[12 + l] = (float)(q[(2 <= l) ? QI(2, l) : QI(l, 2)] * invden);
            #pragma unroll
            for (int l = 0; l < 6; ++l) oo[18 + l] = (float)(q[(3 <= l) ? QI(3, l) : QI(l, 3)] * invden);
        } else {
            #pragma unroll
            for (int l = 0; l < 6; ++l) oo[24 + l] = (float)(q[(4 <= l) ? QI(4, l) : QI(l, 4)] * invden);
            #pragma unroll
            for (int l = 0; l < 6; ++l) oo[30 + l] = (float)(q[(5 <= l) ? QI(5, l) : QI(l, 5)] * invden);
        }
    }
}

extern "C" void kernel_launch(void* const* d_in, const int* in_sizes, int n_in,
                              void* d_out, int out_size, void* d_ws, size_t ws_size,
                              hipStream_t stream) {
    const float* Mg = (const float*)d_in[0];  // [64,2048,13,13] fp32
    const float* Tg = (const float*)d_in[1];  // [64,2048,4,4]  fp32
    float* out = (float*)d_out;               // [NPROB*16 + NPROB*36] fp32
    (void)in_sizes; (void)n_in; (void)out_size; (void)d_ws; (void)ws_size;

    const int threads = 256;               // 4 waves, all on the same 64 problems
    const int blocks  = NPROB / 64;        // 2048
    gn5_kernel<<<blocks, threads, 0, stream>>>(Mg, Tg, out);
}

// Round 6
// 248.903 us; speedup vs baseline: 1.1685x; 1.1575x over previous
//
#include <hip/hip_runtime.h>
#include <math.h>

#define NPROB (64 * 2048)

__host__ __device__ constexpr int TRI(int i, int j) { return i * 13 - i * (i - 1) / 2 + (j - i); }
__host__ __device__ constexpr int OI3(int i, int j) { return i * 3 - i * (i - 1) / 2 + (j - i); }
__host__ __device__ constexpr int QI(int i, int j)  { return i * 7 - i * (i - 1) / 2 + (j - i); }

// One thread = one problem (R3 structure). This round: ILP surgery —
// split accumulators (chains ~6 -> ~3) + Schur 3x3 solve (chain ~50 -> ~22).
// fp64 reorder is safe: threshold ~2e7, reorder error <= ~1e3.
__global__ __launch_bounds__(256) void gn5_kernel(const float* __restrict__ Mg,
                                                  const float* __restrict__ Tg,
                                                  float* __restrict__ outg) {
    const int tid  = threadIdx.x;
    const int lane = tid & 63;
    const int wv   = tid >> 6;
    const long long prob = (long long)blockIdx.x * 256 + tid;

    __shared__ __align__(16) float buf[64 * 169];
    float mreg[91];

    #pragma unroll 1
    for (int w = 0; w < 4; ++w) {
        const long long c0 = (long long)blockIdx.x * 256 + (long long)w * 64;
        const float4* src = (const float4*)(Mg + c0 * 169);
        float4* dst = (float4*)buf;
        #pragma unroll 1
        for (int i = tid; i < (64 * 169) / 4; i += 256) dst[i] = src[i];
        __syncthreads();
        if (wv == w) {
            #pragma unroll
            for (int i = 0; i < 13; ++i)
                #pragma unroll
                for (int j = i; j < 13; ++j)
                    mreg[TRI(i, j)] = buf[lane * 169 + i * 13 + j];
        }
        __syncthreads();
    }

    double t[3][4];
    {
        const float* tp = Tg + prob * 16;
        #pragma unroll
        for (int i = 0; i < 3; ++i)
            #pragma unroll
            for (int j = 0; j < 4; ++j)
                t[i][j] = (double)tp[i * 4 + j];
    }

    double q[28];  // 7x7 upper triangle of Q/Omega

    #pragma unroll 1
    for (int it = 0; it < 5; ++it) {
        // ===== build: two independent accumulator sets =====
        double yA[13], yB[13];
        double qaaD[6], qaaO[6], qab[9], qbb[6];
        #pragma unroll
        for (int j = 0; j < 13; ++j) { yA[j] = 0.0; yB[j] = 0.0; }
        #pragma unroll
        for (int j = 0; j < 6; ++j) { qaaD[j] = 0.0; qaaO[j] = 0.0; qbb[j] = 0.0; }
        #pragma unroll
        for (int j = 0; j < 9; ++j) qab[j] = 0.0;

        // ---- diag rot blocks (i,i): disjoint yA slots, qaaD chain 3 ----
        #pragma unroll
        for (int i = 0; i < 3; ++i) {
            double md[3][3];
            #pragma unroll
            for (int r = 0; r < 3; ++r)
                #pragma unroll
                for (int s = r; s < 3; ++s) {
                    const double v = (double)mreg[TRI(3 * i + r, 3 * i + s)];
                    md[r][s] = v; md[s][r] = v;
                }
            const double jx = t[i][0], jy = t[i][1], jz = t[i][2];
            #pragma unroll
            for (int r = 0; r < 3; ++r)
                yA[3 * i + r] += md[r][0] * jx + md[r][1] * jy + md[r][2] * jz;
            double X[3][3], Z[3][3];
            #pragma unroll
            for (int r = 0; r < 3; ++r) {
                X[r][0] = md[r][1] * jz - md[r][2] * jy;
                X[r][1] = md[r][2] * jx - md[r][0] * jz;
                X[r][2] = md[r][0] * jy - md[r][1] * jx;
            }
            #pragma unroll
            for (int l = 0; l < 3; ++l) {
                Z[0][l] = X[1][l] * jz - X[2][l] * jy;
                Z[1][l] = X[2][l] * jx - X[0][l] * jz;
                Z[2][l] = X[0][l] * jy - X[1][l] * jx;
            }
            #pragma unroll
            for (int k = 0; k < 3; ++k)
                #pragma unroll
                for (int l = k; l < 3; ++l) qaaD[OI3(k, l)] += Z[k][l];
        }

        // ---- off rot blocks (i<j): yB, qaaO (independent of diag set) ----
        #pragma unroll
        for (int i = 0; i < 3; ++i)
            #pragma unroll
            for (int j = i + 1; j < 3; ++j) {
                double md[3][3];
                #pragma unroll
                for (int r = 0; r < 3; ++r)
                    #pragma unroll
                    for (int c = 0; c < 3; ++c)
                        md[r][c] = (double)mreg[TRI(3 * i + r, 3 * j + c)];
                const double jx = t[j][0], jy = t[j][1], jz = t[j][2];
                const double ix = t[i][0], iy = t[i][1], iz = t[i][2];
                #pragma unroll
                for (int r = 0; r < 3; ++r)
                    yB[3 * i + r] += md[r][0] * jx + md[r][1] * jy + md[r][2] * jz;
                #pragma unroll
                for (int c = 0; c < 3; ++c)
                    yB[3 * j + c] += md[0][c] * ix + md[1][c] * iy + md[2][c] * iz;
                double X[3][3], Z[3][3];
                #pragma unroll
                for (int r = 0; r < 3; ++r) {
                    X[r][0] = md[r][1] * jz - md[r][2] * jy;
                    X[r][1] = md[r][2] * jx - md[r][0] * jz;
                    X[r][2] = md[r][0] * jy - md[r][1] * jx;
                }
                #pragma unroll
                for (int l = 0; l < 3; ++l) {
                    Z[0][l] = X[1][l] * iz - X[2][l] * iy;
                    Z[1][l] = X[2][l] * ix - X[0][l] * iz;
                    Z[2][l] = X[0][l] * iy - X[1][l] * ix;
                }
                #pragma unroll
                for (int k = 0; k < 3; ++k)
                    #pragma unroll
                    for (int l = k; l < 3; ++l) qaaO[OI3(k, l)] += Z[k][l] + Z[l][k];
            }

        // ---- rot-trans blocks i=0..2: yB + qab ----
        #pragma unroll
        for (int i = 0; i < 3; ++i) {
            double md[3][3];
            #pragma unroll
            for (int r = 0; r < 3; ++r)
                #pragma unroll
                for (int c = 0; c < 3; ++c)
                    md[r][c] = (double)mreg[TRI(3 * i + r, 10 + c)];
            const double ix = t[i][0], iy = t[i][1], iz = t[i][2];
            #pragma unroll
            for (int r = 0; r < 3; ++r)
                yB[3 * i + r] += md[r][0] * t[0][3] + md[r][1] * t[1][3] + md[r][2] * t[2][3];
            #pragma unroll
            for (int c = 0; c < 3; ++c)
                yB[10 + c] += md[0][c] * ix + md[1][c] * iy + md[2][c] * iz;
            double W[3][3];
            #pragma unroll
            for (int r = 0; r < 3; ++r)
                #pragma unroll
                for (int c = 0; c < 3; ++c)
                    W[r][c] = md[r][0] * t[0][c] + md[r][1] * t[1][c] + md[r][2] * t[2][c];
            #pragma unroll
            for (int c = 0; c < 3; ++c) {
                qab[0 * 3 + c] += W[1][c] * iz - W[2][c] * iy;
                qab[1 * 3 + c] += W[2][c] * ix - W[0][c] * iz;
                qab[2 * 3 + c] += W[0][c] * iy - W[1][c] * ix;
            }
        }

        // ---- ones row (row/col 9): yA, y9 via tree ----
        {
            const double n0 = (double)mreg[TRI(0, 9)], n1 = (double)mreg[TRI(1, 9)];
            const double n2 = (double)mreg[TRI(2, 9)], n3 = (double)mreg[TRI(3, 9)];
            const double n4 = (double)mreg[TRI(4, 9)], n5 = (double)mreg[TRI(5, 9)];
            const double n6 = (double)mreg[TRI(6, 9)], n7 = (double)mreg[TRI(7, 9)];
            const double n8 = (double)mreg[TRI(8, 9)], n9 = (double)mreg[TRI(9, 9)];
            const double na = (double)mreg[TRI(9, 10)], nb = (double)mreg[TRI(9, 11)];
            const double nc = (double)mreg[TRI(9, 12)];
            yA[0] += n0; yA[1] += n1; yA[2] += n2;
            yA[3] += n3; yA[4] += n4; yA[5] += n5;
            yA[6] += n6; yA[7] += n7; yA[8] += n8;
            yA[10] += na; yA[11] += nb; yA[12] += nc;
            const double s0 = n0 * t[0][0] + n1 * t[0][1];
            const double s1 = n2 * t[0][2] + n3 * t[1][0];
            const double s2 = n4 * t[1][1] + n5 * t[1][2];
            const double s3 = n6 * t[2][0] + n7 * t[2][1];
            const double s4 = n8 * t[2][2] + n9;
            const double s5 = na * t[0][3] + nb * t[1][3];
            const double s6 = nc * t[2][3];
            yA[9] = ((s0 + s1) + (s2 + s3)) + ((s4 + s5) + s6);
        }

        // ---- trans-trans Mtt: yA + qbb ----
        {
            double mt[3][3];
            #pragma unroll
            for (int r = 0; r < 3; ++r)
                #pragma unroll
                for (int s = r; s < 3; ++s) {
                    const double v = (double)mreg[TRI(10 + r, 10 + s)];
                    mt[r][s] = v; mt[s][r] = v;
                }
            #pragma unroll
            for (int r = 0; r < 3; ++r)
                yA[10 + r] += mt[r][0] * t[0][3] + mt[r][1] * t[1][3] + mt[r][2] * t[2][3];
            double wb[3][3];
            #pragma unroll
            for (int r = 0; r < 3; ++r)
                #pragma unroll
                for (int c = 0; c < 3; ++c)
                    wb[r][c] = mt[r][0] * t[0][c] + mt[r][1] * t[1][c] + mt[r][2] * t[2][c];
            #pragma unroll
            for (int k = 0; k < 3; ++k)
                #pragma unroll
                for (int l = k; l < 3; ++l)
                    qbb[OI3(k, l)] += t[0][k] * wb[0][l] + t[1][k] * wb[1][l] + t[2][k] * wb[2][l];
        }

        // ---- combine sets ----
        double y6[13];
        #pragma unroll
        for (int j = 0; j < 13; ++j) y6[j] = yA[j] + yB[j];
        #pragma unroll
        for (int k = 0; k < 3; ++k)
            #pragma unroll
            for (int l = k; l < 3; ++l) {
                q[QI(k, l)] = qaaD[OI3(k, l)] + qaaO[OI3(k, l)];
                q[QI(3 + k, 3 + l)] = qbb[OI3(k, l)];
            }
        #pragma unroll
        for (int k = 0; k < 3; ++k)
            #pragma unroll
            for (int c = 0; c < 3; ++c) q[QI(k, 3 + c)] = qab[k * 3 + c];

        // ---- last column of Q (tree-structured) ----
        {
            const double g0 = t[0][0] * y6[0] + t[0][1] * y6[1] + t[0][2] * y6[2];
            const double g1 = t[1][0] * y6[3] + t[1][1] * y6[4] + t[1][2] * y6[5];
            const double g2 = t[2][0] * y6[6] + t[2][1] * y6[7] + t[2][2] * y6[8];
            const double g3 = t[0][3] * y6[10] + t[1][3] * y6[11] + t[2][3] * y6[12];
            q[QI(6, 6)] = ((g0 + g1) + (g2 + g3)) + y6[9];
            double qa0 = 0.0, qa1 = 0.0, qa2 = 0.0;
            #pragma unroll
            for (int i = 0; i < 3; ++i) {
                const double v0 = y6[3 * i + 0], v1 = y6[3 * i + 1], v2 = y6[3 * i + 2];
                qa0 += v1 * t[i][2] - v2 * t[i][1];
                qa1 += v2 * t[i][0] - v0 * t[i][2];
                qa2 += v0 * t[i][1] - v1 * t[i][0];
            }
            q[QI(0, 6)] = qa0; q[QI(1, 6)] = qa1; q[QI(2, 6)] = qa2;
            #pragma unroll
            for (int k = 0; k < 3; ++k)
                q[QI(3 + k, 6)] = t[0][k] * y6[10] + t[1][k] * y6[11] + t[2][k] * y6[12];
        }

        // ---- regularization (reference-exact) ----
        const double trQ  = q[QI(3, 3)] + q[QI(4, 4)] + q[QI(5, 5)];
        const double regT = 1e-8 * fmax(trQ, 1.0);
        q[QI(0, 0)] += 10.0;
        q[QI(1, 1)] += 10.0;
        q[QI(2, 2)] += 10.0;
        q[QI(3, 3)] += regT;
        q[QI(4, 4)] += regT;
        q[QI(5, 5)] += regT;

        // ---- reg2 = 1e-5*(1+max(Omega)) via shallow fmax tree ----
        double mxa = fmax(fmax(q[QI(0, 0)], q[QI(0, 1)]), fmax(q[QI(0, 2)], q[QI(0, 3)]));
        double mxb = fmax(fmax(q[QI(0, 4)], q[QI(0, 5)]), fmax(q[QI(1, 1)], q[QI(1, 2)]));
        double mxc = fmax(fmax(q[QI(1, 3)], q[QI(1, 4)]), fmax(q[QI(1, 5)], q[QI(2, 2)]));
        double mxd = fmax(fmax(q[QI(2, 3)], q[QI(2, 4)]), fmax(q[QI(2, 5)], q[QI(3, 3)]));
        double mxe = fmax(fmax(q[QI(3, 4)], q[QI(3, 5)]), fmax(q[QI(4, 4)], q[QI(4, 5)]));
        double mxf = q[QI(5, 5)];
        const double mx = fmax(fmax(mxa, mxb), fmax(mxc, fmax(mxd, fmax(mxe, mxf))));
        const double reg2 = 1e-5 * (1.0 + mx);

        // ---- Schur solve: (Omega+reg2 I) x = g, x = [xa;xb], v = -x ----
        const double a00 = q[QI(0, 0)] + reg2, a01 = q[QI(0, 1)], a02 = q[QI(0, 2)];
        const double a11 = q[QI(1, 1)] + reg2, a12 = q[QI(1, 2)];
        const double a22 = q[QI(2, 2)] + reg2;
        const double B00 = q[QI(0, 3)], B01 = q[QI(0, 4)], B02 = q[QI(0, 5)];
        const double B10 = q[QI(1, 3)], B11 = q[QI(1, 4)], B12 = q[QI(1, 5)];
        const double B20 = q[QI(2, 3)], B21 = q[QI(2, 4)], B22 = q[QI(2, 5)];
        const double c00 = q[QI(3, 3)] + reg2, c01 = q[QI(3, 4)], c02 = q[QI(3, 5)];
        const double c11 = q[QI(4, 4)] + reg2, c12 = q[QI(4, 5)];
        const double c22 = q[QI(5, 5)] + reg2;
        const double ga0 = q[QI(0, 6)], ga1 = q[QI(1, 6)], ga2 = q[QI(2, 6)];
        const double gb0 = q[QI(3, 6)], gb1 = q[QI(4, 6)], gb2 = q[QI(5, 6)];

        // Ai = A^{-1} (adjugate; A is SPD: diag has +10+reg2)
        const double k00 = a11 * a22 - a12 * a12;
        const double k01 = a02 * a12 - a01 * a22;
        const double k02 = a01 * a12 - a02 * a11;
        const double k11 = a00 * a22 - a02 * a02;
        const double k12 = a01 * a02 - a00 * a12;
        const double k22 = a00 * a11 - a01 * a01;
        const double detA = a00 * k00 + (a01 * k01 + a02 * k02);
        const double dAi = 1.0 / detA;
        const double Ai00 = k00 * dAi, Ai01 = k01 * dAi, Ai02 = k02 * dAi;
        const double Ai11 = k11 * dAi, Ai12 = k12 * dAi, Ai22 = k22 * dAi;

        // W = Ai * B
        const double W00 = Ai00 * B00 + Ai01 * B10 + Ai02 * B20;
        const double W01 = Ai00 * B01 + Ai01 * B11 + Ai02 * B21;
        const double W02 = Ai00 * B02 + Ai01 * B12 + Ai02 * B22;
        const double W10 = Ai01 * B00 + Ai11 * B10 + Ai12 * B20;
        const double W11 = Ai01 * B01 + Ai11 * B11 + Ai12 * B21;
        const double W12 = Ai01 * B02 + Ai11 * B12 + Ai12 * B22;
        const double W20 = Ai02 * B00 + Ai12 * B10 + Ai22 * B20;
        const double W21 = Ai02 * B01 + Ai12 * B11 + Ai22 * B21;
        const double W22 = Ai02 * B02 + Ai12 * B12 + Ai22 * B22;

        // S = C - B^T W (symmetric)
        const double S00 = c00 - (B00 * W00 + B10 * W10 + B20 * W20);
        const double S01 = c01 - (B00 * W01 + B10 * W11 + B20 * W21);
        const double S02 = c02 - (B00 * W02 + B10 * W12 + B20 * W22);
        const double S11 = c11 - (B01 * W01 + B11 * W11 + B21 * W21);
        const double S12 = c12 - (B01 * W02 + B11 * W12 + B21 * W22);
        const double S22 = c22 - (B02 * W02 + B12 * W12 + B22 * W22);

        // Si = S^{-1}
        const double m00 = S11 * S22 - S12 * S12;
        const double m01 = S02 * S12 - S01 * S22;
        const double m02 = S01 * S12 - S02 * S11;
        const double m11 = S00 * S22 - S02 * S02;
        const double m12 = S01 * S02 - S00 * S12;
        const double m22 = S00 * S11 - S01 * S01;
        const double detS = S00 * m00 + (S01 * m01 + S02 * m02);
        const double dSi = 1.0 / detS;
        const double Si00 = m00 * dSi, Si01 = m01 * dSi, Si02 = m02 * dSi;
        const double Si11 = m11 * dSi, Si12 = m12 * dSi, Si22 = m22 * dSi;

        // v1 = Ai ga; h = gb - B^T v1; xb = Si h; xa = v1 - W xb
        const double v10 = Ai00 * ga0 + Ai01 * ga1 + Ai02 * ga2;
        const double v11 = Ai01 * ga0 + Ai11 * ga1 + Ai12 * ga2;
        const double v12 = Ai02 * ga0 + Ai12 * ga1 + Ai22 * ga2;
        const double h0 = gb0 - (B00 * v10 + B10 * v11 + B20 * v12);
        const double h1 = gb1 - (B01 * v10 + B11 * v11 + B21 * v12);
        const double h2 = gb2 - (B02 * v10 + B12 * v11 + B22 * v12);
        const double xb0 = Si00 * h0 + Si01 * h1 + Si02 * h2;
        const double xb1 = Si01 * h0 + Si11 * h1 + Si12 * h2;
        const double xb2 = Si02 * h0 + Si12 * h1 + Si22 * h2;
        const double xa0 = v10 - (W00 * xb0 + W01 * xb1 + W02 * xb2);
        const double xa1 = v11 - (W10 * xb0 + W11 * xb1 + W12 * xb2);
        const double xa2 = v12 - (W20 * xb0 + W21 * xb1 + W22 * xb2);

        const double wx = -xa0, wy = -xa1, wz = -xa2;
        const double ux = -xb0, uy = -xb1, uz = -xb2;

        // ---- closed-form expm of se(3): E = [[R, V*u],[0,1]] ----
        const double tsq = wx * wx + wy * wy + wz * wz;
        double A, B, Cc;
        if (tsq < 1.0) {
            A  = 1.0 + tsq * (-1.0/6 + tsq * (1.0/120 + tsq * (-1.0/5040 + tsq * (1.0/362880
                 + tsq * (-1.0/39916800.0 + tsq * (1.0/6227020800.0 + tsq * (-1.0/1307674368000.0
                 + tsq * (1.0/355687428096000.0))))))));
            B  = 0.5 + tsq * (-1.0/24 + tsq * (1.0/720 + tsq * (-1.0/40320 + tsq * (1.0/3628800
                 + tsq * (-1.0/479001600.0 + tsq * (1.0/87178291200.0 + tsq * (-1.0/20922789888000.0
                 + tsq * (1.0/6402373705728000.0))))))));
            Cc = 1.0/6 + tsq * (-1.0/120 + tsq * (1.0/5040 + tsq * (-1.0/362880 + tsq * (1.0/39916800.0
                 + tsq * (-1.0/6227020800.0 + tsq * (1.0/1307674368000.0 + tsq * (-1.0/355687428096000.0
                 + tsq * (1.0/121645100408832000.0))))))));
        } else {
            const double th = sqrt(tsq);
            const double s = sin(th), c = cos(th);
            A  = s / th;
            B  = (1.0 - c) / tsq;
            Cc = (th - s) / (tsq * th);
        }
        const double K2xx = wx * wx - tsq, K2yy = wy * wy - tsq, K2zz = wz * wz - tsq;
        const double K2xy = wx * wy, K2xz = wx * wz, K2yz = wy * wz;
        double R[3][3];
        R[0][0] = 1.0 + B * K2xx;      R[0][1] = -A * wz + B * K2xy;  R[0][2] =  A * wy + B * K2xz;
        R[1][0] =  A * wz + B * K2xy;  R[1][1] = 1.0 + B * K2yy;      R[1][2] = -A * wx + B * K2yz;
        R[2][0] = -A * wy + B * K2xz;  R[2][1] =  A * wx + B * K2yz;  R[2][2] = 1.0 + B * K2zz;
        const double V00 = 1.0 + Cc * K2xx,      V01 = -B * wz + Cc * K2xy, V02 =  B * wy + Cc * K2xz;
        const double V10 =  B * wz + Cc * K2xy,  V11 = 1.0 + Cc * K2yy,     V12 = -B * wx + Cc * K2yz;
        const double V20 = -B * wy + Cc * K2xz,  V21 =  B * wx + Cc * K2yz, V22 = 1.0 + Cc * K2zz;
        const double ex = V00 * ux + V01 * uy + V02 * uz;
        const double ey = V10 * ux + V11 * uy + V12 * uz;
        const double ez = V20 * ux + V21 * uy + V22 * uz;

        // ---- T = T @ E ----
        #pragma unroll
        for (int i = 0; i < 3; ++i) {
            const double a0 = t[i][0], a1 = t[i][1], a2 = t[i][2], a3 = t[i][3];
            t[i][0] = a0 * R[0][0] + a1 * R[1][0] + a2 * R[2][0];
            t[i][1] = a0 * R[0][1] + a1 * R[1][1] + a2 * R[2][1];
            t[i][2] = a0 * R[0][2] + a1 * R[1][2] + a2 * R[2][2];
            t[i][3] = a0 * ex + a1 * ey + a2 * ez + a3;
        }
        // q holds Omega (with diag d, without reg2) for the epilogue.
    }

    // ---- outputs: T [.,4,4] then Omega/(tz^2+1e-8) [.,6,6], fp32 ----
    {
        float* to = outg + prob * 16;
        #pragma unroll
        for (int i = 0; i < 3; ++i)
            #pragma unroll
            for (int j = 0; j < 4; ++j)
                to[i * 4 + j] = (float)t[i][j];
        to[12] = 0.0f; to[13] = 0.0f; to[14] = 0.0f; to[15] = 1.0f;

        const double invden = 1.0 / (t[2][3] * t[2][3] + 1e-8);
        float* oo = outg + (long long)NPROB * 16 + prob * 36;
        #pragma unroll
        for (int k = 0; k < 6; ++k)
            #pragma unroll
            for (int l = 0; l < 6; ++l)
                oo[k * 6 + l] = (float)(q[(k <= l) ? QI(k, l) : QI(l, k)] * invden);
    }
}

extern "C" void kernel_launch(void* const* d_in, const int* in_sizes, int n_in,
                              void* d_out, int out_size, void* d_ws, size_t ws_size,
                              hipStream_t stream) {
    const float* Mg = (const float*)d_in[0];  // [64,2048,13,13] fp32
    const float* Tg = (const float*)d_in[1];  // [64,2048,4,4]  fp32
    float* out = (float*)d_out;               // [NPROB*16 + NPROB*36] fp32
    (void)in_sizes; (void)n_in; (void)out_size; (void)d_ws; (void)ws_size;

    const int threads = 256;
    const int blocks = NPROB / threads;  // 512
    gn5_kernel<<<blocks, threads, 0, stream>>>(Mg, Tg, out);
}